// Round 7
// baseline (290.401 us; speedup 1.0000x reference)
//
#include <hip/hip_runtime.h>

#define BATCH 4
#define NPTS  8192
#define FDIM  64
#define BK    64
#define NT    (NPTS / BK)

typedef _Float16 half_t;
typedef half_t half8  __attribute__((ext_vector_type(8)));
typedef half_t half2v __attribute__((ext_vector_type(2)));
typedef float  f32x4  __attribute__((ext_vector_type(4)));
typedef float  f32x16 __attribute__((ext_vector_type(16)));
typedef unsigned uint4v __attribute__((ext_vector_type(4)));
typedef unsigned uint2v __attribute__((ext_vector_type(2)));

__device__ inline unsigned pkrtz(float a, float b) {
    return __builtin_bit_cast(unsigned, __builtin_amdgcn_cvt_pkrtz(a, b));
}
__device__ inline half2v h2(unsigned u) { return __builtin_bit_cast(half2v, u); }

// swap(a,b): new a = [a.lo | b.lo], new b = [a.hi | b.hi]  (lane halves)
__device__ inline uint2v plswap(unsigned a, unsigned b) {
    return __builtin_amdgcn_permlane32_swap(a, b, false, false);
}

// ---------------- prep (R2-proven structure, branch-free): one thread per (b,n)
// q[b][n][f]=fp16(x[b][f][n]); vt[b][o][n]=fp16(sum_f x*w); nrm[b][n]=||x||^2*log2e
__global__ __launch_bounds__(128) void prep_kernel(
    const float* __restrict__ x, const float* __restrict__ w,
    half_t* __restrict__ q, half_t* __restrict__ vt, float* __restrict__ nrm)
{
    __shared__ float wl[FDIM * FDIM];
    int t = threadIdx.x;
    #pragma unroll
    for (int i = 0; i < (FDIM * FDIM) / 128; ++i)
        wl[i * 128 + t] = w[i * 128 + t];
    __syncthreads();

    int gid = blockIdx.x * 128 + t;          // one (b, n) per thread
    int b = gid >> 13;
    int n = gid & (NPTS - 1);
    const float* xb = x + (size_t)b * FDIM * NPTS + n;

    float acc[FDIM];
    #pragma unroll
    for (int o = 0; o < FDIM; ++o) acc[o] = 0.0f;
    float nr = 0.0f;

    half8* qrow = (half8*)(q + (size_t)gid * FDIM);
    #pragma unroll
    for (int f8 = 0; f8 < 8; ++f8) {
        half8 h;
        #pragma unroll
        for (int j = 0; j < 8; ++j) {
            int f = f8 * 8 + j;
            float xv = xb[(size_t)f * NPTS];          // coalesced across lanes
            nr += xv * xv;
            h[j] = (half_t)xv;
            const f32x4* wr = (const f32x4*)&wl[f * FDIM];   // broadcast (conflict-free)
            #pragma unroll
            for (int o4 = 0; o4 < FDIM / 4; ++o4) {
                f32x4 wv = wr[o4];
                acc[o4*4+0] += xv * wv[0];
                acc[o4*4+1] += xv * wv[1];
                acc[o4*4+2] += xv * wv[2];
                acc[o4*4+3] += xv * wv[3];
            }
        }
        qrow[f8] = h;
    }
    nrm[gid] = nr * 1.44269504f;
    half_t* vb = vt + (size_t)b * FDIM * NPTS + n;
    #pragma unroll
    for (int o = 0; o < FDIM; ++o)
        vb[(size_t)o * NPTS] = (half_t)acc[o];        // coalesced across lanes
}

// ---------------- flash attention, 32x32 MFMA, fixed-max softmax, split-KV
// S^T = mfma32(K, Q^T) with C preset to -m2; ct-pipelined (half of S/pkv live);
// P via permlane32_swap in-register; O^T = mfma32(V^T, P^T).
// Staging: reg-staged VGPR loads + swizzled ds_write (L2-served re-reads — NOT
// global_load_lds, which bypassed L2 reuse and exploded FETCH in R6).
template<int SPLIT>
__global__ __launch_bounds__(256, 3) void flash_kernel(
    const half_t* __restrict__ qk, const half_t* __restrict__ vt,
    const float* __restrict__ nrm, float* __restrict__ out,
    half_t* __restrict__ part, float* __restrict__ lbuf)
{
    constexpr int TPS   = NT / SPLIT;
    constexpr int TOTAL = BATCH * SPLIT * (NPTS / 256);

    __shared__ half_t kl[2][BK * FDIM];    // K tile  [kv][granule-swizzled f]
    __shared__ half_t vl[2][BK * FDIM];    // V^T tile [o][granule-swizzled kv]

    int t    = threadIdx.x;
    int lane = t & 63;
    int l31  = lane & 31;
    int hi   = lane >> 5;
    int w    = t >> 6;                     // wave 0..3

    int blk0 = blockIdx.x;
    int blk  = (blk0 & 7) * (TOTAL / 8) + (blk0 >> 3);   // XCD swizzle (TOTAL%8==0)
    int qc   = blk & 31;                                 // q chunk (256 rows)
    int rest = blk >> 5;
    int s    = rest & (SPLIT - 1);
    int b    = rest / SPLIT;
    int qw   = qc * 256 + w * 64;                        // 64 q rows per wave

    const half_t* kg = qk + (size_t)b * NPTS * FDIM;
    const half_t* vg = vt + (size_t)b * FDIM * NPTS;

    // Q B-frags (pre-scaled by log2 e): B[f = c*16 + hi*8 + j][q = qt*32 + l31]
    half8 qf[2][4];
    #pragma unroll
    for (int qt = 0; qt < 2; ++qt)
        #pragma unroll
        for (int c = 0; c < 4; ++c) {
            qf[qt][c] = *(const half8*)(kg + (size_t)(qw + qt*32 + l31) * FDIM + c*16 + hi*8);
            qf[qt][c] = qf[qt][c] * (half_t)1.44269504f;
        }

    float m2[2];
    #pragma unroll
    for (int qt = 0; qt < 2; ++qt)
        m2[qt] = nrm[(size_t)b * NPTS + qw + qt*32 + l31];

    // staging: 512 16B-chunks per array, 2 per thread per array; swizzled LDS dest
    int r0 = t >> 3, g0 = t & 7;
    int r1 = r0 + 32;
    int li0 = r0 * FDIM + ((g0 ^ (r0 & 7)) * 8);
    int li1 = r1 * FDIM + ((g0 ^ (r1 & 7)) * 8);

    int kb0 = s * TPS * BK;
    half8 s0 = *(const half8*)(kg + (size_t)(kb0 + r0) * FDIM + g0*8);
    half8 s1 = *(const half8*)(kg + (size_t)(kb0 + r1) * FDIM + g0*8);
    half8 s2 = *(const half8*)(vg + (size_t)r0 * NPTS + kb0 + g0*8);
    half8 s3 = *(const half8*)(vg + (size_t)r1 * NPTS + kb0 + g0*8);

    f32x16 O[2][2];
    #pragma unroll
    for (int ot = 0; ot < 2; ++ot)
        #pragma unroll
        for (int qt = 0; qt < 2; ++qt)
            #pragma unroll
            for (int r = 0; r < 16; ++r) O[ot][qt][r] = 0.0f;
    float lsum[2] = {0.0f, 0.0f};

    for (int tt = 0; tt < TPS; ++tt) {
        half_t* klb = kl[tt & 1];
        half_t* vlb = vl[tt & 1];
        *(half8*)(klb + li0) = s0;
        *(half8*)(klb + li1) = s1;
        *(half8*)(vlb + li0) = s2;
        *(half8*)(vlb + li1) = s3;
        if (tt + 1 < TPS) {                // prefetch stays in flight across barrier
            int kb = kb0 + (tt + 1) * BK;
            s0 = *(const half8*)(kg + (size_t)(kb + r0) * FDIM + g0*8);
            s1 = *(const half8*)(kg + (size_t)(kb + r1) * FDIM + g0*8);
            s2 = *(const half8*)(vg + (size_t)r0 * NPTS + kb + g0*8);
            s3 = *(const half8*)(vg + (size_t)r1 * NPTS + kb + g0*8);
        }
        __syncthreads();                   // writes visible; prev-tile readers done

        #pragma unroll
        for (int ct = 0; ct < 2; ++ct) {
            // ---- S^T = K x Q^T for this ct (C preset to -m2 folds max subtraction)
            f32x16 S[2];
            #pragma unroll
            for (int r = 0; r < 16; ++r) { S[0][r] = -m2[0]; S[1][r] = -m2[1]; }
            int krow = ct * 32 + l31;
            __builtin_amdgcn_s_setprio(1);
            #pragma unroll
            for (int c = 0; c < 4; ++c) {
                half8 kf = *(const half8*)(klb + krow * FDIM + (((2*c + hi) ^ (krow & 7)) * 8));
                S[0] = __builtin_amdgcn_mfma_f32_32x32x16_f16(kf, qf[0][c], S[0], 0, 0, 0);
                S[1] = __builtin_amdgcn_mfma_f32_32x32x16_f16(kf, qf[1][c], S[1], 0, 0, 0);
            }
            __builtin_amdgcn_s_setprio(0);

            // ---- p = exp2(S); pack to fp16 (RTZ saturates); lsum from packed fp16
            unsigned pk[2][8];
            #pragma unroll
            for (int qt = 0; qt < 2; ++qt) {
                #pragma unroll
                for (int rr = 0; rr < 8; ++rr)
                    pk[qt][rr] = pkrtz(__builtin_amdgcn_exp2f(S[qt][2*rr]),
                                       __builtin_amdgcn_exp2f(S[qt][2*rr+1]));
                half2v s2v = ((h2(pk[qt][0]) + h2(pk[qt][1])) + (h2(pk[qt][2]) + h2(pk[qt][3])))
                           + ((h2(pk[qt][4]) + h2(pk[qt][5])) + (h2(pk[qt][6]) + h2(pk[qt][7])));
                lsum[qt] += (float)s2v[0] + (float)s2v[1];
            }

            // ---- O^T += V^T x P^T for kt = 2ct, 2ct+1 (pk for this ct only)
            #pragma unroll
            for (int ktl = 0; ktl < 2; ++ktl) {
                const int kt = ct * 2 + ktl, i0 = ktl * 4;
                half8 pb[2];
                #pragma unroll
                for (int qt = 0; qt < 2; ++qt) {
                    uint2v r02 = plswap(pk[qt][i0+0], pk[qt][i0+2]);
                    uint2v r13 = plswap(pk[qt][i0+1], pk[qt][i0+3]);
                    uint4v uu; uu[0] = r02[0]; uu[1] = r13[0]; uu[2] = r02[1]; uu[3] = r13[1];
                    pb[qt] = __builtin_bit_cast(half8, uu);
                }
                int vrow0 = l31, vrow1 = 32 + l31;
                half8 vf0 = *(const half8*)(vlb + vrow0 * FDIM + (((2*kt + hi) ^ (vrow0 & 7)) * 8));
                half8 vf1 = *(const half8*)(vlb + vrow1 * FDIM + (((2*kt + hi) ^ (vrow1 & 7)) * 8));
                __builtin_amdgcn_s_setprio(1);
                O[0][0] = __builtin_amdgcn_mfma_f32_32x32x16_f16(vf0, pb[0], O[0][0], 0, 0, 0);
                O[0][1] = __builtin_amdgcn_mfma_f32_32x32x16_f16(vf0, pb[1], O[0][1], 0, 0, 0);
                O[1][0] = __builtin_amdgcn_mfma_f32_32x32x16_f16(vf1, pb[0], O[1][0], 0, 0, 0);
                O[1][1] = __builtin_amdgcn_mfma_f32_32x32x16_f16(vf1, pb[1], O[1][1], 0, 0, 0);
                __builtin_amdgcn_s_setprio(0);
            }
        }
    }

    // final row-sum reduce across lane halves (cols duplicated at l31 / l31+32)
    lsum[0] += __shfl_xor(lsum[0], 32);
    lsum[1] += __shfl_xor(lsum[1], 32);

    if constexpr (SPLIT == 1) {
        float inv[2] = {1.0f / lsum[0], 1.0f / lsum[1]};
        size_t ob = (size_t)b * FDIM * NPTS;
        #pragma unroll
        for (int qt = 0; qt < 2; ++qt)
            #pragma unroll
            for (int ot = 0; ot < 2; ++ot)
                #pragma unroll
                for (int r = 0; r < 16; ++r) {
                    int o = ot*32 + (r & 3) + 8*(r >> 2) + 4*hi;
                    out[ob + (size_t)o * NPTS + qw + qt*32 + l31] = O[ot][qt][r] * inv[qt];
                }
    } else {
        half_t* pbase = part + (size_t)(s * BATCH + b) * FDIM * NPTS;
        #pragma unroll
        for (int qt = 0; qt < 2; ++qt)
            #pragma unroll
            for (int ot = 0; ot < 2; ++ot)
                #pragma unroll
                for (int r = 0; r < 16; ++r) {
                    int o = ot*32 + (r & 3) + 8*(r >> 2) + 4*hi;
                    pbase[(size_t)o * NPTS + qw + qt*32 + l31] = (half_t)O[ot][qt][r];
                }
        if (hi == 0) {
            float* lb = lbuf + (size_t)(s * BATCH + b) * NPTS + qw;
            lb[l31]      = lsum[0];
            lb[32 + l31] = lsum[1];
        }
    }
}

// ---------------- combine: out = sum_s part_s / sum_s l_s (shared fixed max -> linear)
template<int SPLIT>
__global__ __launch_bounds__(256) void combine_kernel(
    const half_t* __restrict__ part, const float* __restrict__ lbuf,
    float* __restrict__ out)
{
    int gid  = blockIdx.x * 256 + threadIdx.x;    // B*F*N/8 threads
    int q8   = gid & (NPTS/8 - 1);
    int rest = gid >> 10;                         // b*64 + o
    int b    = rest >> 6;
    size_t ro = (size_t)rest * NPTS + (size_t)q8 * 8;

    float acc[8], ls[8];
    #pragma unroll
    for (int j = 0; j < 8; ++j) { acc[j] = 0.0f; ls[j] = 0.0f; }
    #pragma unroll
    for (int s = 0; s < SPLIT; ++s) {
        half8 pv = *(const half8*)(part + (size_t)s * BATCH * FDIM * NPTS + ro);
        const float* lb = lbuf + (size_t)(s * BATCH + b) * NPTS + (size_t)q8 * 8;
        #pragma unroll
        for (int j = 0; j < 8; ++j) { acc[j] += (float)pv[j]; ls[j] += lb[j]; }
    }
    #pragma unroll
    for (int j = 0; j < 8; ++j) acc[j] /= ls[j];
    *(f32x4*)(out + ro)     = *(f32x4*)&acc[0];
    *(f32x4*)(out + ro + 4) = *(f32x4*)&acc[4];
}

extern "C" void kernel_launch(void* const* d_in, const int* in_sizes, int n_in,
                              void* d_out, int out_size, void* d_ws, size_t ws_size,
                              hipStream_t stream) {
    (void)in_sizes; (void)n_in; (void)out_size;
    const float* x = (const float*)d_in[0];
    const float* w = (const float*)d_in[1];
    float* out = (float*)d_out;

    const size_t qelems = (size_t)BATCH * NPTS * FDIM;
    half_t* q  = (half_t*)d_ws;                                  // 4 MB
    half_t* vt = q + qelems;                                     // 4 MB
    float* nrm = (float*)((char*)d_ws + 2 * qelems * sizeof(half_t));   // 128 KB
    half_t* part = (half_t*)(nrm + (size_t)BATCH * NPTS);

    const size_t part_elems = (size_t)BATCH * FDIM * NPTS;       // per split (fp16)
    const size_t l_elems    = (size_t)BATCH * NPTS;              // per split (f32)
    const size_t base_bytes = 2 * qelems * sizeof(half_t) + (size_t)BATCH * NPTS * sizeof(float);
    const size_t per_split  = part_elems * sizeof(half_t) + l_elems * sizeof(float);

    int split = 1;
    if (ws_size >= base_bytes + 8 * per_split)      split = 8;
    else if (ws_size >= base_bytes + 4 * per_split) split = 4;
    else if (ws_size >= base_bytes + 2 * per_split) split = 2;
    float* lbuf = (float*)(part + (size_t)split * part_elems);

    prep_kernel<<<(BATCH * NPTS) / 128, 128, 0, stream>>>(x, w, q, vt, nrm);

    if (split == 8) {
        flash_kernel<8><<<BATCH * 8 * (NPTS / 256), 256, 0, stream>>>(q, vt, nrm, out, part, lbuf);
        combine_kernel<8><<<(BATCH * FDIM * NPTS) / 8 / 256, 256, 0, stream>>>(part, lbuf, out);
    } else if (split == 4) {
        flash_kernel<4><<<BATCH * 4 * (NPTS / 256), 256, 0, stream>>>(q, vt, nrm, out, part, lbuf);
        combine_kernel<4><<<(BATCH * FDIM * NPTS) / 8 / 256, 256, 0, stream>>>(part, lbuf, out);
    } else if (split == 2) {
        flash_kernel<2><<<BATCH * 2 * (NPTS / 256), 256, 0, stream>>>(q, vt, nrm, out, part, lbuf);
        combine_kernel<2><<<(BATCH * FDIM * NPTS) / 8 / 256, 256, 0, stream>>>(part, lbuf, out);
    } else {
        flash_kernel<1><<<BATCH * 1 * (NPTS / 256), 256, 0, stream>>>(q, vt, nrm, out, nullptr, nullptr);
    }
}

// Round 8
// 259.893 us; speedup vs baseline: 1.1174x; 1.1174x over previous
//
#include <hip/hip_runtime.h>

#define BATCH 4
#define NPTS  8192
#define FDIM  64
#define BK    64
#define NT    (NPTS / BK)

typedef _Float16 half_t;
typedef half_t half8  __attribute__((ext_vector_type(8)));
typedef half_t half2v __attribute__((ext_vector_type(2)));
typedef float  f32x4  __attribute__((ext_vector_type(4)));
typedef float  f32x16 __attribute__((ext_vector_type(16)));
typedef unsigned uint4v __attribute__((ext_vector_type(4)));
typedef unsigned uint2v __attribute__((ext_vector_type(2)));

__device__ inline unsigned pkrtz(float a, float b) {
    return __builtin_bit_cast(unsigned, __builtin_amdgcn_cvt_pkrtz(a, b));
}
__device__ inline half2v h2(unsigned u) { return __builtin_bit_cast(half2v, u); }

// swap(a,b): new a = [a.lo | b.lo], new b = [a.hi | b.hi]  (lane halves)
__device__ inline uint2v plswap(unsigned a, unsigned b) {
    return __builtin_amdgcn_permlane32_swap(a, b, false, false);
}

// ---------------- prep (R2-proven structure, branch-free): one thread per (b,n)
// q[b][n][f]=fp16(x[b][f][n]); vt[b][o][n]=fp16(sum_f x*w); nrm[b][n]=||x||^2*log2e
__global__ __launch_bounds__(128) void prep_kernel(
    const float* __restrict__ x, const float* __restrict__ w,
    half_t* __restrict__ q, half_t* __restrict__ vt, float* __restrict__ nrm)
{
    __shared__ float wl[FDIM * FDIM];
    int t = threadIdx.x;
    #pragma unroll
    for (int i = 0; i < (FDIM * FDIM) / 128; ++i)
        wl[i * 128 + t] = w[i * 128 + t];
    __syncthreads();

    int gid = blockIdx.x * 128 + t;          // one (b, n) per thread
    int b = gid >> 13;
    int n = gid & (NPTS - 1);
    const float* xb = x + (size_t)b * FDIM * NPTS + n;

    float acc[FDIM];
    #pragma unroll
    for (int o = 0; o < FDIM; ++o) acc[o] = 0.0f;
    float nr = 0.0f;

    half8* qrow = (half8*)(q + (size_t)gid * FDIM);
    #pragma unroll
    for (int f8 = 0; f8 < 8; ++f8) {
        half8 h;
        #pragma unroll
        for (int j = 0; j < 8; ++j) {
            int f = f8 * 8 + j;
            float xv = xb[(size_t)f * NPTS];          // coalesced across lanes
            nr += xv * xv;
            h[j] = (half_t)xv;
            const f32x4* wr = (const f32x4*)&wl[f * FDIM];   // broadcast (conflict-free)
            #pragma unroll
            for (int o4 = 0; o4 < FDIM / 4; ++o4) {
                f32x4 wv = wr[o4];
                acc[o4*4+0] += xv * wv[0];
                acc[o4*4+1] += xv * wv[1];
                acc[o4*4+2] += xv * wv[2];
                acc[o4*4+3] += xv * wv[3];
            }
        }
        qrow[f8] = h;
    }
    nrm[gid] = nr * 1.44269504f;
    half_t* vb = vt + (size_t)b * FDIM * NPTS + n;
    #pragma unroll
    for (int o = 0; o < FDIM; ++o)
        vb[(size_t)o * NPTS] = (half_t)acc[o];        // coalesced across lanes
}

// ---------------- flash attention, 32x32 MFMA, fixed-max softmax, split-KV
// Memory config = R5-proven: SPLIT<=4 (grid <= 512 = one residency wave, so the
// hw blk%8->XCD round-robin holds and per-XCD KV slices stay L2-resident),
// f32 partials (full-line stores, no RFO). Compute = ct-pipelined, packed lsum.
template<int SPLIT>
__global__ __launch_bounds__(256, 3) void flash_kernel(
    const half_t* __restrict__ qk, const half_t* __restrict__ vt,
    const float* __restrict__ nrm, float* __restrict__ out,
    float* __restrict__ part, float* __restrict__ lbuf)
{
    constexpr int TPS   = NT / SPLIT;
    constexpr int TOTAL = BATCH * SPLIT * (NPTS / 256);

    __shared__ half_t kl[2][BK * FDIM];    // K tile  [kv][granule-swizzled f]
    __shared__ half_t vl[2][BK * FDIM];    // V^T tile [o][granule-swizzled kv]

    int t    = threadIdx.x;
    int lane = t & 63;
    int l31  = lane & 31;
    int hi   = lane >> 5;
    int w    = t >> 6;                     // wave 0..3

    int blk0 = blockIdx.x;
    int blk  = (blk0 & 7) * (TOTAL / 8) + (blk0 >> 3);   // XCD swizzle (TOTAL%8==0)
    int qc   = blk & 31;                                 // q chunk (256 rows)
    int rest = blk >> 5;
    int s    = rest & (SPLIT - 1);
    int b    = rest / SPLIT;
    int qw   = qc * 256 + w * 64;                        // 64 q rows per wave

    const half_t* kg = qk + (size_t)b * NPTS * FDIM;
    const half_t* vg = vt + (size_t)b * FDIM * NPTS;

    // Q B-frags (pre-scaled by log2 e): B[f = c*16 + hi*8 + j][q = qt*32 + l31]
    half8 qf[2][4];
    #pragma unroll
    for (int qt = 0; qt < 2; ++qt)
        #pragma unroll
        for (int c = 0; c < 4; ++c) {
            qf[qt][c] = *(const half8*)(kg + (size_t)(qw + qt*32 + l31) * FDIM + c*16 + hi*8);
            qf[qt][c] = qf[qt][c] * (half_t)1.44269504f;
        }

    float m2[2];
    #pragma unroll
    for (int qt = 0; qt < 2; ++qt)
        m2[qt] = nrm[(size_t)b * NPTS + qw + qt*32 + l31];

    // staging: 512 16B-chunks per array, 2 per thread per array; swizzled LDS dest
    int r0 = t >> 3, g0 = t & 7;
    int r1 = r0 + 32;
    int li0 = r0 * FDIM + ((g0 ^ (r0 & 7)) * 8);
    int li1 = r1 * FDIM + ((g0 ^ (r1 & 7)) * 8);

    int kb0 = s * TPS * BK;
    half8 s0 = *(const half8*)(kg + (size_t)(kb0 + r0) * FDIM + g0*8);
    half8 s1 = *(const half8*)(kg + (size_t)(kb0 + r1) * FDIM + g0*8);
    half8 s2 = *(const half8*)(vg + (size_t)r0 * NPTS + kb0 + g0*8);
    half8 s3 = *(const half8*)(vg + (size_t)r1 * NPTS + kb0 + g0*8);

    f32x16 O[2][2];
    #pragma unroll
    for (int ot = 0; ot < 2; ++ot)
        #pragma unroll
        for (int qt = 0; qt < 2; ++qt)
            #pragma unroll
            for (int r = 0; r < 16; ++r) O[ot][qt][r] = 0.0f;
    float lsum[2] = {0.0f, 0.0f};

    for (int tt = 0; tt < TPS; ++tt) {
        half_t* klb = kl[tt & 1];
        half_t* vlb = vl[tt & 1];
        *(half8*)(klb + li0) = s0;
        *(half8*)(klb + li1) = s1;
        *(half8*)(vlb + li0) = s2;
        *(half8*)(vlb + li1) = s3;
        if (tt + 1 < TPS) {                // prefetch stays in flight across barrier
            int kb = kb0 + (tt + 1) * BK;
            s0 = *(const half8*)(kg + (size_t)(kb + r0) * FDIM + g0*8);
            s1 = *(const half8*)(kg + (size_t)(kb + r1) * FDIM + g0*8);
            s2 = *(const half8*)(vg + (size_t)r0 * NPTS + kb + g0*8);
            s3 = *(const half8*)(vg + (size_t)r1 * NPTS + kb + g0*8);
        }
        __syncthreads();                   // writes visible; prev-tile readers done

        #pragma unroll
        for (int ct = 0; ct < 2; ++ct) {
            // ---- S^T = K x Q^T for this ct (C preset to -m2 folds max subtraction)
            f32x16 S[2];
            #pragma unroll
            for (int r = 0; r < 16; ++r) { S[0][r] = -m2[0]; S[1][r] = -m2[1]; }
            int krow = ct * 32 + l31;
            __builtin_amdgcn_s_setprio(1);
            #pragma unroll
            for (int c = 0; c < 4; ++c) {
                half8 kf = *(const half8*)(klb + krow * FDIM + (((2*c + hi) ^ (krow & 7)) * 8));
                S[0] = __builtin_amdgcn_mfma_f32_32x32x16_f16(kf, qf[0][c], S[0], 0, 0, 0);
                S[1] = __builtin_amdgcn_mfma_f32_32x32x16_f16(kf, qf[1][c], S[1], 0, 0, 0);
            }
            __builtin_amdgcn_s_setprio(0);

            // ---- p = exp2(S); pack to fp16 (RTZ saturates); lsum via packed fp16 adds
            unsigned pk[2][8];
            #pragma unroll
            for (int qt = 0; qt < 2; ++qt) {
                #pragma unroll
                for (int rr = 0; rr < 8; ++rr)
                    pk[qt][rr] = pkrtz(__builtin_amdgcn_exp2f(S[qt][2*rr]),
                                       __builtin_amdgcn_exp2f(S[qt][2*rr+1]));
                half2v s2v = ((h2(pk[qt][0]) + h2(pk[qt][1])) + (h2(pk[qt][2]) + h2(pk[qt][3])))
                           + ((h2(pk[qt][4]) + h2(pk[qt][5])) + (h2(pk[qt][6]) + h2(pk[qt][7])));
                lsum[qt] += (float)s2v[0] + (float)s2v[1];
            }

            // ---- O^T += V^T x P^T for kt = 2ct, 2ct+1 (pk for this ct only)
            #pragma unroll
            for (int ktl = 0; ktl < 2; ++ktl) {
                const int kt = ct * 2 + ktl, i0 = ktl * 4;
                half8 pb[2];
                #pragma unroll
                for (int qt = 0; qt < 2; ++qt) {
                    uint2v r02 = plswap(pk[qt][i0+0], pk[qt][i0+2]);
                    uint2v r13 = plswap(pk[qt][i0+1], pk[qt][i0+3]);
                    uint4v uu; uu[0] = r02[0]; uu[1] = r13[0]; uu[2] = r02[1]; uu[3] = r13[1];
                    pb[qt] = __builtin_bit_cast(half8, uu);
                }
                int vrow0 = l31, vrow1 = 32 + l31;
                half8 vf0 = *(const half8*)(vlb + vrow0 * FDIM + (((2*kt + hi) ^ (vrow0 & 7)) * 8));
                half8 vf1 = *(const half8*)(vlb + vrow1 * FDIM + (((2*kt + hi) ^ (vrow1 & 7)) * 8));
                __builtin_amdgcn_s_setprio(1);
                O[0][0] = __builtin_amdgcn_mfma_f32_32x32x16_f16(vf0, pb[0], O[0][0], 0, 0, 0);
                O[0][1] = __builtin_amdgcn_mfma_f32_32x32x16_f16(vf0, pb[1], O[0][1], 0, 0, 0);
                O[1][0] = __builtin_amdgcn_mfma_f32_32x32x16_f16(vf1, pb[0], O[1][0], 0, 0, 0);
                O[1][1] = __builtin_amdgcn_mfma_f32_32x32x16_f16(vf1, pb[1], O[1][1], 0, 0, 0);
                __builtin_amdgcn_s_setprio(0);
            }
        }
    }

    // final row-sum reduce across lane halves (cols duplicated at l31 / l31+32)
    lsum[0] += __shfl_xor(lsum[0], 32);
    lsum[1] += __shfl_xor(lsum[1], 32);

    if constexpr (SPLIT == 1) {
        float inv[2] = {1.0f / lsum[0], 1.0f / lsum[1]};
        size_t ob = (size_t)b * FDIM * NPTS;
        #pragma unroll
        for (int qt = 0; qt < 2; ++qt)
            #pragma unroll
            for (int ot = 0; ot < 2; ++ot)
                #pragma unroll
                for (int r = 0; r < 16; ++r) {
                    int o = ot*32 + (r & 3) + 8*(r >> 2) + 4*hi;
                    out[ob + (size_t)o * NPTS + qw + qt*32 + l31] = O[ot][qt][r] * inv[qt];
                }
    } else {
        float* pbase = part + (size_t)(s * BATCH + b) * FDIM * NPTS;
        #pragma unroll
        for (int qt = 0; qt < 2; ++qt)
            #pragma unroll
            for (int ot = 0; ot < 2; ++ot)
                #pragma unroll
                for (int r = 0; r < 16; ++r) {
                    int o = ot*32 + (r & 3) + 8*(r >> 2) + 4*hi;
                    pbase[(size_t)o * NPTS + qw + qt*32 + l31] = O[ot][qt][r];   // full-line f32 stores
                }
        if (hi == 0) {
            float* lb = lbuf + (size_t)(s * BATCH + b) * NPTS + qw;
            lb[l31]      = lsum[0];
            lb[32 + l31] = lsum[1];
        }
    }
}

// ---------------- combine: out = sum_s part_s / sum_s l_s (shared fixed max -> linear)
template<int SPLIT>
__global__ __launch_bounds__(256) void combine_kernel(
    const float* __restrict__ part, const float* __restrict__ lbuf,
    float* __restrict__ out)
{
    int gid  = blockIdx.x * 256 + threadIdx.x;    // B*F*N/4 float4s
    int q4   = gid & (NPTS/4 - 1);
    int rest = gid >> 11;                         // b*64 + o
    int b    = rest >> 6;
    size_t ro = (size_t)rest * NPTS + (size_t)q4 * 4;

    f32x4 acc = {0,0,0,0}, ls = {0,0,0,0};
    #pragma unroll
    for (int s = 0; s < SPLIT; ++s) {
        acc += *(const f32x4*)(part + (size_t)s * BATCH * FDIM * NPTS + ro);
        ls  += *(const f32x4*)(lbuf + (size_t)(s * BATCH + b) * NPTS + (size_t)q4 * 4);
    }
    *(f32x4*)(out + ro) = acc / ls;
}

extern "C" void kernel_launch(void* const* d_in, const int* in_sizes, int n_in,
                              void* d_out, int out_size, void* d_ws, size_t ws_size,
                              hipStream_t stream) {
    (void)in_sizes; (void)n_in; (void)out_size;
    const float* x = (const float*)d_in[0];
    const float* w = (const float*)d_in[1];
    float* out = (float*)d_out;

    const size_t qelems = (size_t)BATCH * NPTS * FDIM;
    half_t* q  = (half_t*)d_ws;                                  // 4 MB
    half_t* vt = q + qelems;                                     // 4 MB
    float* nrm = (float*)((char*)d_ws + 2 * qelems * sizeof(half_t));   // 128 KB
    float* part = nrm + (size_t)BATCH * NPTS;

    const size_t part_elems = (size_t)BATCH * FDIM * NPTS;       // per split (f32)
    const size_t l_elems    = (size_t)BATCH * NPTS;              // per split (f32)
    const size_t base_bytes = 2 * qelems * sizeof(half_t) + (size_t)BATCH * NPTS * sizeof(float);
    const size_t per_split  = (part_elems + l_elems) * sizeof(float);

    int split = 1;
    if (ws_size >= base_bytes + 4 * per_split)      split = 4;
    else if (ws_size >= base_bytes + 2 * per_split) split = 2;
    float* lbuf = part + (size_t)split * part_elems;

    prep_kernel<<<(BATCH * NPTS) / 128, 128, 0, stream>>>(x, w, q, vt, nrm);

    if (split == 4) {
        flash_kernel<4><<<BATCH * 4 * (NPTS / 256), 256, 0, stream>>>(q, vt, nrm, out, part, lbuf);
        combine_kernel<4><<<(BATCH * FDIM * NPTS) / 4 / 256, 256, 0, stream>>>(part, lbuf, out);
    } else if (split == 2) {
        flash_kernel<2><<<BATCH * 2 * (NPTS / 256), 256, 0, stream>>>(q, vt, nrm, out, part, lbuf);
        combine_kernel<2><<<(BATCH * FDIM * NPTS) / 4 / 256, 256, 0, stream>>>(part, lbuf, out);
    } else {
        flash_kernel<1><<<BATCH * 1 * (NPTS / 256), 256, 0, stream>>>(q, vt, nrm, out, nullptr, nullptr);
    }
}

// Round 9
// 96.909 us; speedup vs baseline: 2.9966x; 2.6818x over previous
//
#include <hip/hip_runtime.h>

#define BATCH 4
#define NPTS  8192
#define FDIM  64
#define BK    64
#define NT    (NPTS / BK)

typedef _Float16 half_t;
typedef half_t half8  __attribute__((ext_vector_type(8)));
typedef half_t half2v __attribute__((ext_vector_type(2)));
typedef float  f32x4  __attribute__((ext_vector_type(4)));
typedef float  f32x16 __attribute__((ext_vector_type(16)));
typedef unsigned uint4v __attribute__((ext_vector_type(4)));
typedef unsigned uint2v __attribute__((ext_vector_type(2)));

__device__ inline unsigned pkrtz(float a, float b) {
    return __builtin_bit_cast(unsigned, __builtin_amdgcn_cvt_pkrtz(a, b));
}
__device__ inline half2v h2(unsigned u) { return __builtin_bit_cast(half2v, u); }

// swap(a,b): new a = [a.lo | b.lo], new b = [a.hi | b.hi]  (lane halves)
__device__ inline uint2v plswap(unsigned a, unsigned b) {
    return __builtin_amdgcn_permlane32_swap(a, b, false, false);
}

// ---------------- prep (R2-proven structure, branch-free): one thread per (b,n)
// q[b][n][f]=fp16(x[b][f][n]); vt[b][o][n]=fp16(sum_f x*w); nrm[b][n]=||x||^2*log2e
__global__ __launch_bounds__(128) void prep_kernel(
    const float* __restrict__ x, const float* __restrict__ w,
    half_t* __restrict__ q, half_t* __restrict__ vt, float* __restrict__ nrm)
{
    __shared__ float wl[FDIM * FDIM];
    int t = threadIdx.x;
    #pragma unroll
    for (int i = 0; i < (FDIM * FDIM) / 128; ++i)
        wl[i * 128 + t] = w[i * 128 + t];
    __syncthreads();

    int gid = blockIdx.x * 128 + t;          // one (b, n) per thread
    int b = gid >> 13;
    int n = gid & (NPTS - 1);
    const float* xb = x + (size_t)b * FDIM * NPTS + n;

    float acc[FDIM];
    #pragma unroll
    for (int o = 0; o < FDIM; ++o) acc[o] = 0.0f;
    float nr = 0.0f;

    half8* qrow = (half8*)(q + (size_t)gid * FDIM);
    #pragma unroll
    for (int f8 = 0; f8 < 8; ++f8) {
        half8 h;
        #pragma unroll
        for (int j = 0; j < 8; ++j) {
            int f = f8 * 8 + j;
            float xv = xb[(size_t)f * NPTS];          // coalesced across lanes
            nr += xv * xv;
            h[j] = (half_t)xv;
            const f32x4* wr = (const f32x4*)&wl[f * FDIM];   // broadcast (conflict-free)
            #pragma unroll
            for (int o4 = 0; o4 < FDIM / 4; ++o4) {
                f32x4 wv = wr[o4];
                acc[o4*4+0] += xv * wv[0];
                acc[o4*4+1] += xv * wv[1];
                acc[o4*4+2] += xv * wv[2];
                acc[o4*4+3] += xv * wv[3];
            }
        }
        qrow[f8] = h;
    }
    nrm[gid] = nr * 1.44269504f;
    half_t* vb = vt + (size_t)b * FDIM * NPTS + n;
    #pragma unroll
    for (int o = 0; o < FDIM; ++o)
        vb[(size_t)o * NPTS] = (half_t)acc[o];        // coalesced across lanes
}

// ---------------- flash attention, 32x32 MFMA, fixed-max softmax, split-KV
// Memory/occupancy config = R5-proven EXACTLY: __launch_bounds__(256,2), grid 512,
// f32 partials, no setprio. (R6-R8 showed (256,3) changes block->XCD packing and
// collapses the swizzle's L2 locality: FETCH 8MB -> 143-383MB.)
// Compute deltas vs R5: ct-pipelined inner loop, packed-fp16 lsum.
template<int SPLIT>
__global__ __launch_bounds__(256, 2) void flash_kernel(
    const half_t* __restrict__ qk, const half_t* __restrict__ vt,
    const float* __restrict__ nrm, float* __restrict__ out,
    float* __restrict__ part, float* __restrict__ lbuf)
{
    constexpr int TPS   = NT / SPLIT;
    constexpr int TOTAL = BATCH * SPLIT * (NPTS / 256);

    __shared__ half_t kl[2][BK * FDIM];    // K tile  [kv][granule-swizzled f]
    __shared__ half_t vl[2][BK * FDIM];    // V^T tile [o][granule-swizzled kv]

    int t    = threadIdx.x;
    int lane = t & 63;
    int l31  = lane & 31;
    int hi   = lane >> 5;
    int w    = t >> 6;                     // wave 0..3

    int blk0 = blockIdx.x;
    int blk  = (blk0 & 7) * (TOTAL / 8) + (blk0 >> 3);   // XCD swizzle (TOTAL%8==0)
    int qc   = blk & 31;                                 // q chunk (256 rows)
    int rest = blk >> 5;
    int s    = rest & (SPLIT - 1);
    int b    = rest / SPLIT;
    int qw   = qc * 256 + w * 64;                        // 64 q rows per wave

    const half_t* kg = qk + (size_t)b * NPTS * FDIM;
    const half_t* vg = vt + (size_t)b * FDIM * NPTS;

    // Q B-frags (pre-scaled by log2 e): B[f = c*16 + hi*8 + j][q = qt*32 + l31]
    half8 qf[2][4];
    #pragma unroll
    for (int qt = 0; qt < 2; ++qt)
        #pragma unroll
        for (int c = 0; c < 4; ++c) {
            qf[qt][c] = *(const half8*)(kg + (size_t)(qw + qt*32 + l31) * FDIM + c*16 + hi*8);
            qf[qt][c] = qf[qt][c] * (half_t)1.44269504f;
        }

    float m2[2];
    #pragma unroll
    for (int qt = 0; qt < 2; ++qt)
        m2[qt] = nrm[(size_t)b * NPTS + qw + qt*32 + l31];

    // staging: 512 16B-chunks per array, 2 per thread per array; swizzled LDS dest
    int r0 = t >> 3, g0 = t & 7;
    int r1 = r0 + 32;
    int li0 = r0 * FDIM + ((g0 ^ (r0 & 7)) * 8);
    int li1 = r1 * FDIM + ((g0 ^ (r1 & 7)) * 8);

    int kb0 = s * TPS * BK;
    half8 s0 = *(const half8*)(kg + (size_t)(kb0 + r0) * FDIM + g0*8);
    half8 s1 = *(const half8*)(kg + (size_t)(kb0 + r1) * FDIM + g0*8);
    half8 s2 = *(const half8*)(vg + (size_t)r0 * NPTS + kb0 + g0*8);
    half8 s3 = *(const half8*)(vg + (size_t)r1 * NPTS + kb0 + g0*8);

    f32x16 O[2][2];
    #pragma unroll
    for (int ot = 0; ot < 2; ++ot)
        #pragma unroll
        for (int qt = 0; qt < 2; ++qt)
            #pragma unroll
            for (int r = 0; r < 16; ++r) O[ot][qt][r] = 0.0f;
    float lsum[2] = {0.0f, 0.0f};

    for (int tt = 0; tt < TPS; ++tt) {
        half_t* klb = kl[tt & 1];
        half_t* vlb = vl[tt & 1];
        *(half8*)(klb + li0) = s0;
        *(half8*)(klb + li1) = s1;
        *(half8*)(vlb + li0) = s2;
        *(half8*)(vlb + li1) = s3;
        if (tt + 1 < TPS) {                // prefetch stays in flight across barrier
            int kb = kb0 + (tt + 1) * BK;
            s0 = *(const half8*)(kg + (size_t)(kb + r0) * FDIM + g0*8);
            s1 = *(const half8*)(kg + (size_t)(kb + r1) * FDIM + g0*8);
            s2 = *(const half8*)(vg + (size_t)r0 * NPTS + kb + g0*8);
            s3 = *(const half8*)(vg + (size_t)r1 * NPTS + kb + g0*8);
        }
        __syncthreads();                   // writes visible; prev-tile readers done

        #pragma unroll
        for (int ct = 0; ct < 2; ++ct) {
            // ---- S^T = K x Q^T for this ct (C preset to -m2 folds max subtraction)
            f32x16 S[2];
            #pragma unroll
            for (int r = 0; r < 16; ++r) { S[0][r] = -m2[0]; S[1][r] = -m2[1]; }
            int krow = ct * 32 + l31;
            #pragma unroll
            for (int c = 0; c < 4; ++c) {
                half8 kf = *(const half8*)(klb + krow * FDIM + (((2*c + hi) ^ (krow & 7)) * 8));
                S[0] = __builtin_amdgcn_mfma_f32_32x32x16_f16(kf, qf[0][c], S[0], 0, 0, 0);
                S[1] = __builtin_amdgcn_mfma_f32_32x32x16_f16(kf, qf[1][c], S[1], 0, 0, 0);
            }

            // ---- p = exp2(S); pack to fp16 (RTZ saturates); lsum via packed fp16 adds
            unsigned pk[2][8];
            #pragma unroll
            for (int qt = 0; qt < 2; ++qt) {
                #pragma unroll
                for (int rr = 0; rr < 8; ++rr)
                    pk[qt][rr] = pkrtz(__builtin_amdgcn_exp2f(S[qt][2*rr]),
                                       __builtin_amdgcn_exp2f(S[qt][2*rr+1]));
                half2v s2v = ((h2(pk[qt][0]) + h2(pk[qt][1])) + (h2(pk[qt][2]) + h2(pk[qt][3])))
                           + ((h2(pk[qt][4]) + h2(pk[qt][5])) + (h2(pk[qt][6]) + h2(pk[qt][7])));
                lsum[qt] += (float)s2v[0] + (float)s2v[1];
            }

            // ---- O^T += V^T x P^T for kt = 2ct, 2ct+1 (pk for this ct only)
            #pragma unroll
            for (int ktl = 0; ktl < 2; ++ktl) {
                const int kt = ct * 2 + ktl, i0 = ktl * 4;
                half8 pb[2];
                #pragma unroll
                for (int qt = 0; qt < 2; ++qt) {
                    uint2v r02 = plswap(pk[qt][i0+0], pk[qt][i0+2]);
                    uint2v r13 = plswap(pk[qt][i0+1], pk[qt][i0+3]);
                    uint4v uu; uu[0] = r02[0]; uu[1] = r13[0]; uu[2] = r02[1]; uu[3] = r13[1];
                    pb[qt] = __builtin_bit_cast(half8, uu);
                }
                int vrow0 = l31, vrow1 = 32 + l31;
                half8 vf0 = *(const half8*)(vlb + vrow0 * FDIM + (((2*kt + hi) ^ (vrow0 & 7)) * 8));
                half8 vf1 = *(const half8*)(vlb + vrow1 * FDIM + (((2*kt + hi) ^ (vrow1 & 7)) * 8));
                O[0][0] = __builtin_amdgcn_mfma_f32_32x32x16_f16(vf0, pb[0], O[0][0], 0, 0, 0);
                O[0][1] = __builtin_amdgcn_mfma_f32_32x32x16_f16(vf0, pb[1], O[0][1], 0, 0, 0);
                O[1][0] = __builtin_amdgcn_mfma_f32_32x32x16_f16(vf1, pb[0], O[1][0], 0, 0, 0);
                O[1][1] = __builtin_amdgcn_mfma_f32_32x32x16_f16(vf1, pb[1], O[1][1], 0, 0, 0);
            }
        }
    }

    // final row-sum reduce across lane halves (cols duplicated at l31 / l31+32)
    lsum[0] += __shfl_xor(lsum[0], 32);
    lsum[1] += __shfl_xor(lsum[1], 32);

    if constexpr (SPLIT == 1) {
        float inv[2] = {1.0f / lsum[0], 1.0f / lsum[1]};
        size_t ob = (size_t)b * FDIM * NPTS;
        #pragma unroll
        for (int qt = 0; qt < 2; ++qt)
            #pragma unroll
            for (int ot = 0; ot < 2; ++ot)
                #pragma unroll
                for (int r = 0; r < 16; ++r) {
                    int o = ot*32 + (r & 3) + 8*(r >> 2) + 4*hi;
                    out[ob + (size_t)o * NPTS + qw + qt*32 + l31] = O[ot][qt][r] * inv[qt];
                }
    } else {
        float* pbase = part + (size_t)(s * BATCH + b) * FDIM * NPTS;
        #pragma unroll
        for (int qt = 0; qt < 2; ++qt)
            #pragma unroll
            for (int ot = 0; ot < 2; ++ot)
                #pragma unroll
                for (int r = 0; r < 16; ++r) {
                    int o = ot*32 + (r & 3) + 8*(r >> 2) + 4*hi;
                    pbase[(size_t)o * NPTS + qw + qt*32 + l31] = O[ot][qt][r];   // full-line f32 stores
                }
        if (hi == 0) {
            float* lb = lbuf + (size_t)(s * BATCH + b) * NPTS + qw;
            lb[l31]      = lsum[0];
            lb[32 + l31] = lsum[1];
        }
    }
}

// ---------------- combine: out = sum_s part_s / sum_s l_s (shared fixed max -> linear)
template<int SPLIT>
__global__ __launch_bounds__(256) void combine_kernel(
    const float* __restrict__ part, const float* __restrict__ lbuf,
    float* __restrict__ out)
{
    int gid  = blockIdx.x * 256 + threadIdx.x;    // B*F*N/4 float4s
    int q4   = gid & (NPTS/4 - 1);
    int rest = gid >> 11;                         // b*64 + o
    int b    = rest >> 6;
    size_t ro = (size_t)rest * NPTS + (size_t)q4 * 4;

    f32x4 acc = {0,0,0,0}, ls = {0,0,0,0};
    #pragma unroll
    for (int s = 0; s < SPLIT; ++s) {
        acc += *(const f32x4*)(part + (size_t)s * BATCH * FDIM * NPTS + ro);
        ls  += *(const f32x4*)(lbuf + (size_t)(s * BATCH + b) * NPTS + (size_t)q4 * 4);
    }
    *(f32x4*)(out + ro) = acc / ls;
}

extern "C" void kernel_launch(void* const* d_in, const int* in_sizes, int n_in,
                              void* d_out, int out_size, void* d_ws, size_t ws_size,
                              hipStream_t stream) {
    (void)in_sizes; (void)n_in; (void)out_size;
    const float* x = (const float*)d_in[0];
    const float* w = (const float*)d_in[1];
    float* out = (float*)d_out;

    const size_t qelems = (size_t)BATCH * NPTS * FDIM;
    half_t* q  = (half_t*)d_ws;                                  // 4 MB
    half_t* vt = q + qelems;                                     // 4 MB
    float* nrm = (float*)((char*)d_ws + 2 * qelems * sizeof(half_t));   // 128 KB
    float* part = nrm + (size_t)BATCH * NPTS;

    const size_t part_elems = (size_t)BATCH * FDIM * NPTS;       // per split (f32)
    const size_t l_elems    = (size_t)BATCH * NPTS;              // per split (f32)
    const size_t base_bytes = 2 * qelems * sizeof(half_t) + (size_t)BATCH * NPTS * sizeof(float);
    const size_t per_split  = (part_elems + l_elems) * sizeof(float);

    int split = 1;
    if (ws_size >= base_bytes + 4 * per_split)      split = 4;
    else if (ws_size >= base_bytes + 2 * per_split) split = 2;
    float* lbuf = part + (size_t)split * part_elems;

    prep_kernel<<<(BATCH * NPTS) / 128, 128, 0, stream>>>(x, w, q, vt, nrm);

    if (split == 4) {
        flash_kernel<4><<<BATCH * 4 * (NPTS / 256), 256, 0, stream>>>(q, vt, nrm, out, part, lbuf);
        combine_kernel<4><<<(BATCH * FDIM * NPTS) / 4 / 256, 256, 0, stream>>>(part, lbuf, out);
    } else if (split == 2) {
        flash_kernel<2><<<BATCH * 2 * (NPTS / 256), 256, 0, stream>>>(q, vt, nrm, out, part, lbuf);
        combine_kernel<2><<<(BATCH * FDIM * NPTS) / 4 / 256, 256, 0, stream>>>(part, lbuf, out);
    } else {
        flash_kernel<1><<<BATCH * 1 * (NPTS / 256), 256, 0, stream>>>(q, vt, nrm, out, nullptr, nullptr);
    }
}

// Round 10
// 95.795 us; speedup vs baseline: 3.0315x; 1.0116x over previous
//
#include <hip/hip_runtime.h>

#define BATCH 4
#define NPTS  8192
#define FDIM  64
#define BK    64
#define NT    (NPTS / BK)

typedef _Float16 half_t;
typedef half_t half8  __attribute__((ext_vector_type(8)));
typedef half_t half2v __attribute__((ext_vector_type(2)));
typedef float  f32x4  __attribute__((ext_vector_type(4)));
typedef float  f32x16 __attribute__((ext_vector_type(16)));
typedef unsigned uint4v __attribute__((ext_vector_type(4)));
typedef unsigned uint2v __attribute__((ext_vector_type(2)));

__device__ inline unsigned pkrtz(float a, float b) {
    return __builtin_bit_cast(unsigned, __builtin_amdgcn_cvt_pkrtz(a, b));
}
__device__ inline half2v h2(unsigned u) { return __builtin_bit_cast(half2v, u); }

// swap(a,b): new a = [a.lo | b.lo], new b = [a.hi | b.hi]  (lane halves)
__device__ inline uint2v plswap(unsigned a, unsigned b) {
    return __builtin_amdgcn_permlane32_swap(a, b, false, false);
}

// ---------------- prep: one thread per (b,n).
// ka = K/Q in FRAGMENT-MAJOR layout: ka[(n/64)*8 + f8][row=n%64][8 halfs of f]
//   (element (n, f=f8*8+j) at ((n>>6)*8+f8)*512 + (n&63)*8 + j) — coalesced stores,
//   and flash reads Q/K MFMA fragments as contiguous 512B segments.
// vt[b][o][n] = fp16(sum_f x*w);  nrm[b][n] = ||x||^2 * log2e
__global__ __launch_bounds__(128) void prep_kernel(
    const float* __restrict__ x, const float* __restrict__ w,
    half_t* __restrict__ ka, half_t* __restrict__ vt, float* __restrict__ nrm)
{
    __shared__ float wl[FDIM * FDIM];
    int t = threadIdx.x;
    #pragma unroll
    for (int i = 0; i < (FDIM * FDIM) / 128; ++i)
        wl[i * 128 + t] = w[i * 128 + t];
    __syncthreads();

    int gid = blockIdx.x * 128 + t;          // one (b, n) per thread
    int b = gid >> 13;
    int n = gid & (NPTS - 1);
    const float* xb = x + (size_t)b * FDIM * NPTS + n;

    float acc[FDIM];
    #pragma unroll
    for (int o = 0; o < FDIM; ++o) acc[o] = 0.0f;
    float nr = 0.0f;

    half_t* kab = ka + (size_t)(gid >> 6) * 4096 + (size_t)(gid & 63) * 8;
    #pragma unroll
    for (int f8 = 0; f8 < 8; ++f8) {
        half8 h;
        #pragma unroll
        for (int j = 0; j < 8; ++j) {
            int f = f8 * 8 + j;
            float xv = xb[(size_t)f * NPTS];          // coalesced across lanes
            nr += xv * xv;
            h[j] = (half_t)xv;
            const f32x4* wr = (const f32x4*)&wl[f * FDIM];   // broadcast (conflict-free)
            #pragma unroll
            for (int o4 = 0; o4 < FDIM / 4; ++o4) {
                f32x4 wv = wr[o4];
                acc[o4*4+0] += xv * wv[0];
                acc[o4*4+1] += xv * wv[1];
                acc[o4*4+2] += xv * wv[2];
                acc[o4*4+3] += xv * wv[3];
            }
        }
        *(half8*)(kab + f8 * 512) = h;               // coalesced (16B x 128 lanes contiguous)
    }
    nrm[gid] = nr * 1.44269504f;
    half_t* vb = vt + (size_t)b * FDIM * NPTS + n;
    #pragma unroll
    for (int o = 0; o < FDIM; ++o)
        vb[(size_t)o * NPTS] = (half_t)acc[o];        // coalesced across lanes
}

// ---------------- flash attention, 32x32 MFMA, fixed-max softmax, split-KV
// Memory/occupancy config = R5/R9-proven EXACTLY: __launch_bounds__(256,2), grid 512,
// f32 partials, no setprio. ((256,3) breaks block->XCD packing: FETCH 8MB->143MB, R8.)
// R10 delta: K fragments read DIRECTLY from global (fragment-major ka, coalesced,
// L1/L2-served) -> K off the LDS pipe; LDS holds only V. Next-tile kf refilled
// right after current ct's QK MFMAs consume it (latency hides under PV).
template<int SPLIT>
__global__ __launch_bounds__(256, 2) void flash_kernel(
    const half_t* __restrict__ qk, const half_t* __restrict__ vt,
    const float* __restrict__ nrm, float* __restrict__ out,
    float* __restrict__ part, float* __restrict__ lbuf)
{
    constexpr int TPS   = NT / SPLIT;
    constexpr int TOTAL = BATCH * SPLIT * (NPTS / 256);

    __shared__ half_t vl[2][BK * FDIM];    // V^T tile [o][granule-swizzled kv]

    int t    = threadIdx.x;
    int lane = t & 63;
    int l31  = lane & 31;
    int hi   = lane >> 5;
    int w    = t >> 6;                     // wave 0..3

    int blk0 = blockIdx.x;
    int blk  = (blk0 & 7) * (TOTAL / 8) + (blk0 >> 3);   // XCD swizzle (TOTAL%8==0)
    int qc   = blk & 31;                                 // q chunk (256 rows)
    int rest = blk >> 5;
    int s    = rest & (SPLIT - 1);
    int b    = rest / SPLIT;
    int qw   = qc * 256 + w * 64;                        // 64 q rows per wave

    const half_t* kg = qk + (size_t)b * NPTS * FDIM;     // fragment-major ka for batch b
    const half_t* vg = vt + (size_t)b * FDIM * NPTS;

    // Q B-frags (pre-scaled by log2 e) from fragment-major layout: contiguous segments
    const half_t* qgb = kg + (size_t)(qw >> 6) * 4096 + (size_t)l31 * 8;
    half8 qf[2][4];
    #pragma unroll
    for (int qt = 0; qt < 2; ++qt)
        #pragma unroll
        for (int c = 0; c < 4; ++c) {
            qf[qt][c] = *(const half8*)(qgb + (c*2 + hi) * 512 + qt * 256);
            qf[qt][c] = qf[qt][c] * (half_t)1.44269504f;
        }

    float m2[2];
    #pragma unroll
    for (int qt = 0; qt < 2; ++qt)
        m2[qt] = nrm[(size_t)b * NPTS + qw + qt*32 + l31];

    // V staging: 512 16B-chunks, 2 per thread; swizzled LDS dest
    int r0 = t >> 3, g0 = t & 7;
    int r1 = r0 + 32;
    int li0 = r0 * FDIM + ((g0 ^ (r0 & 7)) * 8);
    int li1 = r1 * FDIM + ((g0 ^ (r1 & 7)) * 8);

    int kb0 = s * TPS * BK;
    half8 s2 = *(const half8*)(vg + (size_t)r0 * NPTS + kb0 + g0*8);
    half8 s3 = *(const half8*)(vg + (size_t)r1 * NPTS + kb0 + g0*8);

    // K fragments for tile 0 (direct global, coalesced)
    half8 kf[2][4];
    {
        const half_t* kgb = kg + (size_t)(kb0 >> 6) * 4096 + (size_t)l31 * 8;
        #pragma unroll
        for (int ct = 0; ct < 2; ++ct)
            #pragma unroll
            for (int c = 0; c < 4; ++c)
                kf[ct][c] = *(const half8*)(kgb + (c*2 + hi) * 512 + ct * 256);
    }

    f32x16 O[2][2];
    #pragma unroll
    for (int ot = 0; ot < 2; ++ot)
        #pragma unroll
        for (int qt = 0; qt < 2; ++qt)
            #pragma unroll
            for (int r = 0; r < 16; ++r) O[ot][qt][r] = 0.0f;
    float lsum[2] = {0.0f, 0.0f};

    for (int tt = 0; tt < TPS; ++tt) {
        half_t* vlb = vl[tt & 1];
        *(half8*)(vlb + li0) = s2;
        *(half8*)(vlb + li1) = s3;
        if (tt + 1 < TPS) {                // V prefetch stays in flight across barrier
            int kb = kb0 + (tt + 1) * BK;
            s2 = *(const half8*)(vg + (size_t)r0 * NPTS + kb + g0*8);
            s3 = *(const half8*)(vg + (size_t)r1 * NPTS + kb + g0*8);
        }
        __syncthreads();                   // V writes visible; prev-tile readers done

        const half_t* kgbn = kg + (size_t)((kb0 + (tt + 1) * BK) >> 6) * 4096 + (size_t)l31 * 8;

        #pragma unroll
        for (int ct = 0; ct < 2; ++ct) {
            // ---- S^T = K x Q^T for this ct (C preset to -m2 folds max subtraction)
            f32x16 S[2];
            #pragma unroll
            for (int r = 0; r < 16; ++r) { S[0][r] = -m2[0]; S[1][r] = -m2[1]; }
            #pragma unroll
            for (int c = 0; c < 4; ++c) {
                S[0] = __builtin_amdgcn_mfma_f32_32x32x16_f16(kf[ct][c], qf[0][c], S[0], 0, 0, 0);
                S[1] = __builtin_amdgcn_mfma_f32_32x32x16_f16(kf[ct][c], qf[1][c], S[1], 0, 0, 0);
            }
            // refill kf[ct] for next tile; latency hides under exp/pack + PV below
            if (tt + 1 < TPS) {
                #pragma unroll
                for (int c = 0; c < 4; ++c)
                    kf[ct][c] = *(const half8*)(kgbn + (c*2 + hi) * 512 + ct * 256);
            }

            // ---- p = exp2(S); pack to fp16 (RTZ saturates); lsum via packed fp16 adds
            unsigned pk[2][8];
            #pragma unroll
            for (int qt = 0; qt < 2; ++qt) {
                #pragma unroll
                for (int rr = 0; rr < 8; ++rr)
                    pk[qt][rr] = pkrtz(__builtin_amdgcn_exp2f(S[qt][2*rr]),
                                       __builtin_amdgcn_exp2f(S[qt][2*rr+1]));
                half2v s2v = ((h2(pk[qt][0]) + h2(pk[qt][1])) + (h2(pk[qt][2]) + h2(pk[qt][3])))
                           + ((h2(pk[qt][4]) + h2(pk[qt][5])) + (h2(pk[qt][6]) + h2(pk[qt][7])));
                lsum[qt] += (float)s2v[0] + (float)s2v[1];
            }

            // ---- O^T += V^T x P^T for kt = 2ct, 2ct+1 (pk for this ct only)
            #pragma unroll
            for (int ktl = 0; ktl < 2; ++ktl) {
                const int kt = ct * 2 + ktl, i0 = ktl * 4;
                half8 pb[2];
                #pragma unroll
                for (int qt = 0; qt < 2; ++qt) {
                    uint2v r02 = plswap(pk[qt][i0+0], pk[qt][i0+2]);
                    uint2v r13 = plswap(pk[qt][i0+1], pk[qt][i0+3]);
                    uint4v uu; uu[0] = r02[0]; uu[1] = r13[0]; uu[2] = r02[1]; uu[3] = r13[1];
                    pb[qt] = __builtin_bit_cast(half8, uu);
                }
                int vrow0 = l31, vrow1 = 32 + l31;
                half8 vf0 = *(const half8*)(vlb + vrow0 * FDIM + (((2*kt + hi) ^ (vrow0 & 7)) * 8));
                half8 vf1 = *(const half8*)(vlb + vrow1 * FDIM + (((2*kt + hi) ^ (vrow1 & 7)) * 8));
                O[0][0] = __builtin_amdgcn_mfma_f32_32x32x16_f16(vf0, pb[0], O[0][0], 0, 0, 0);
                O[0][1] = __builtin_amdgcn_mfma_f32_32x32x16_f16(vf0, pb[1], O[0][1], 0, 0, 0);
                O[1][0] = __builtin_amdgcn_mfma_f32_32x32x16_f16(vf1, pb[0], O[1][0], 0, 0, 0);
                O[1][1] = __builtin_amdgcn_mfma_f32_32x32x16_f16(vf1, pb[1], O[1][1], 0, 0, 0);
            }
        }
    }

    // final row-sum reduce across lane halves (cols duplicated at l31 / l31+32)
    lsum[0] += __shfl_xor(lsum[0], 32);
    lsum[1] += __shfl_xor(lsum[1], 32);

    if constexpr (SPLIT == 1) {
        float inv[2] = {1.0f / lsum[0], 1.0f / lsum[1]};
        size_t ob = (size_t)b * FDIM * NPTS;
        #pragma unroll
        for (int qt = 0; qt < 2; ++qt)
            #pragma unroll
            for (int ot = 0; ot < 2; ++ot)
                #pragma unroll
                for (int r = 0; r < 16; ++r) {
                    int o = ot*32 + (r & 3) + 8*(r >> 2) + 4*hi;
                    out[ob + (size_t)o * NPTS + qw + qt*32 + l31] = O[ot][qt][r] * inv[qt];
                }
    } else {
        float* pbase = part + (size_t)(s * BATCH + b) * FDIM * NPTS;
        #pragma unroll
        for (int qt = 0; qt < 2; ++qt)
            #pragma unroll
            for (int ot = 0; ot < 2; ++ot)
                #pragma unroll
                for (int r = 0; r < 16; ++r) {
                    int o = ot*32 + (r & 3) + 8*(r >> 2) + 4*hi;
                    pbase[(size_t)o * NPTS + qw + qt*32 + l31] = O[ot][qt][r];   // full-line f32 stores
                }
        if (hi == 0) {
            float* lb = lbuf + (size_t)(s * BATCH + b) * NPTS + qw;
            lb[l31]      = lsum[0];
            lb[32 + l31] = lsum[1];
        }
    }
}

// ---------------- combine: out = sum_s part_s / sum_s l_s (shared fixed max -> linear)
template<int SPLIT>
__global__ __launch_bounds__(256) void combine_kernel(
    const float* __restrict__ part, const float* __restrict__ lbuf,
    float* __restrict__ out)
{
    int gid  = blockIdx.x * 256 + threadIdx.x;    // B*F*N/4 float4s
    int q4   = gid & (NPTS/4 - 1);
    int rest = gid >> 11;                         // b*64 + o
    int b    = rest >> 6;
    size_t ro = (size_t)rest * NPTS + (size_t)q4 * 4;

    f32x4 acc = {0,0,0,0}, ls = {0,0,0,0};
    #pragma unroll
    for (int s = 0; s < SPLIT; ++s) {
        acc += *(const f32x4*)(part + (size_t)s * BATCH * FDIM * NPTS + ro);
        ls  += *(const f32x4*)(lbuf + (size_t)(s * BATCH + b) * NPTS + (size_t)q4 * 4);
    }
    *(f32x4*)(out + ro) = acc / ls;
}

extern "C" void kernel_launch(void* const* d_in, const int* in_sizes, int n_in,
                              void* d_out, int out_size, void* d_ws, size_t ws_size,
                              hipStream_t stream) {
    (void)in_sizes; (void)n_in; (void)out_size;
    const float* x = (const float*)d_in[0];
    const float* w = (const float*)d_in[1];
    float* out = (float*)d_out;

    const size_t qelems = (size_t)BATCH * NPTS * FDIM;
    half_t* ka = (half_t*)d_ws;                                  // 4 MB (fragment-major K/Q)
    half_t* vt = ka + qelems;                                    // 4 MB
    float* nrm = (float*)((char*)d_ws + 2 * qelems * sizeof(half_t));   // 128 KB
    float* part = nrm + (size_t)BATCH * NPTS;

    const size_t part_elems = (size_t)BATCH * FDIM * NPTS;       // per split (f32)
    const size_t l_elems    = (size_t)BATCH * NPTS;              // per split (f32)
    const size_t base_bytes = 2 * qelems * sizeof(half_t) + (size_t)BATCH * NPTS * sizeof(float);
    const size_t per_split  = (part_elems + l_elems) * sizeof(float);

    int split = 1;
    if (ws_size >= base_bytes + 4 * per_split)      split = 4;
    else if (ws_size >= base_bytes + 2 * per_split) split = 2;
    float* lbuf = part + (size_t)split * part_elems;

    prep_kernel<<<(BATCH * NPTS) / 128, 128, 0, stream>>>(x, w, ka, vt, nrm);

    if (split == 4) {
        flash_kernel<4><<<BATCH * 4 * (NPTS / 256), 256, 0, stream>>>(ka, vt, nrm, out, part, lbuf);
        combine_kernel<4><<<(BATCH * FDIM * NPTS) / 4 / 256, 256, 0, stream>>>(part, lbuf, out);
    } else if (split == 2) {
        flash_kernel<2><<<BATCH * 2 * (NPTS / 256), 256, 0, stream>>>(ka, vt, nrm, out, part, lbuf);
        combine_kernel<2><<<(BATCH * FDIM * NPTS) / 4 / 256, 256, 0, stream>>>(part, lbuf, out);
    } else {
        flash_kernel<1><<<BATCH * 1 * (NPTS / 256), 256, 0, stream>>>(ka, vt, nrm, out, nullptr, nullptr);
    }
}